// Round 5
// baseline (124.777 us; speedup 1.0000x reference)
//
#include <hip/hip_runtime.h>

// KDE entropy loss, MI355X/gfx950 — fp8 fused GEMM, symmetric pairs once,
// wrapped-diagonal mapping. R12: occupancy play. R11 showed 45% dual-idle
// at 4 waves/SIMD (2 blocks/CU, LDS-limited). Switch wave tile 32x64 ->
// 16x64 using mfma_scale_f32_16x16x128_f8f6f4 (same fp8 rate): per-wave
// regs areg 32->16, acc 32->16, rs 16->4 => ~56 VGPR, fits 64-reg/8-wave
// budget. Block = 1024 thr (16 waves, 128x128 tile), LDS 64KB dbuf
// unchanged -> 2 blocks/CU = 32 waves/CU (100% wave occupancy, was 16).
// Same grid/pair-map/staging/chunk layout as verified R7. Colsum = one
// coalesced 64-lane atomic per wave (lane-select of 4 coltile sums).
// ws: [0,4MiB) Xn fp8 [16384][256]; [4MiB,+64KiB) density f32; then ticket u32.

#define NROWS 16384
#define KDIM 256            // bytes per fp8 row
#define NTILE 128
#define NT (NROWS / NTILE)  // 128 tile rows
#define NSTRIP 4
#define TOTAL_BLOCKS (NT * NSTRIP)  // 512 blocks of 1024 thr = exactly 2 per CU

// sqrt(5 * log2(e)): folded into both operands -> sim scaled by 5*log2(e),
// so kernel = exp2(sim_scaled) = exp(5*sim).
#define SQRT_KLOG2E 2.68579577857f

typedef int i32x4_t __attribute__((ext_vector_type(4)));
typedef int i32x8_t __attribute__((ext_vector_type(8)));
typedef float f32x2_t __attribute__((ext_vector_type(2)));
typedef float f32x4_t __attribute__((ext_vector_type(4)));
typedef __attribute__((address_space(1))) const void global_cvoid_t;
typedef __attribute__((address_space(3))) void lds_void_t;

#if __has_builtin(__builtin_amdgcn_exp2f)
#define EXP2(x) __builtin_amdgcn_exp2f(x)
#else
#define EXP2(x) exp2f(x)
#endif

union frag32 { i32x8_t v8; i32x4_t v4[2]; };  // 32B/lane MFMA operand

// One wave per row: sqrt(5log2e)/max(||x||,eps), fp8 e4m3 out; zero density+ticket.
__global__ __launch_bounds__(256)
void kde_normalize(const float* __restrict__ X, unsigned int* __restrict__ Xn8,
                   float* __restrict__ density, unsigned int* __restrict__ ticket) {
  const int wave = threadIdx.x >> 6;
  const int lane = threadIdx.x & 63;
  const int row = blockIdx.x * 4 + wave;
  const float4 v = ((const float4*)(X + (size_t)row * KDIM))[lane];
  float ss = v.x * v.x + v.y * v.y + v.z * v.z + v.w * v.w;
  ss += __shfl_xor(ss, 1);
  ss += __shfl_xor(ss, 2);
  ss += __shfl_xor(ss, 4);
  ss += __shfl_xor(ss, 8);
  ss += __shfl_xor(ss, 16);
  ss += __shfl_xor(ss, 32);
  const float scale = SQRT_KLOG2E / fmaxf(sqrtf(ss), 1e-12f);
  int p = 0;
  p = __builtin_amdgcn_cvt_pk_fp8_f32(v.x * scale, v.y * scale, p, false);
  p = __builtin_amdgcn_cvt_pk_fp8_f32(v.z * scale, v.w * scale, p, true);
  Xn8[(size_t)row * 64 + lane] = (unsigned int)p;
  if (threadIdx.x < 4) density[blockIdx.x * 4 + threadIdx.x] = 0.0f;
  if (blockIdx.x == 0 && threadIdx.x == 0) *ticket = 0u;
}

// Block (bi, s): row tile bi; J = (bi+t) mod 128 for t in [s*16, s*16+16)
// (+ t=64 for s==0, bi<64 — dispatched first so the 17-iter blocks start
// earliest). Each unordered tile pair once. 16 waves 8x2 over 128x128; wave
// = 16 rows x 64 cols = 4 coltiles x (2 chained mfma 16x16x128). A in regs
// (16 VGPR); B double-buffers in 64 KB LDS; 1 barrier/iter; in-loop global
// colsum atomics (measured free — R8/R10 LDS-colsum variants regressed).
//
// LDS chunk layout (identical to verified R7 staging): chunk c = rt*8+kb*2+hh
// holds rows [rt*32, +32) x K-bytes [kb*64 + hh*16, +16) at offset
// c*1024 + h*512 + m32*16 where the staging lane = h*32+m32.
// Byte A[R][KB] -> ((R>>5)*8 + (KB>>6)*2 + ((KB>>4)&1))*1024
//                  + ((KB>>5)&1)*512 + (R&31)*16 + (KB&15).
// 16x16x128 fragment layout (analogy to verified 32x32x64 row=lane&31,
// K-half=lane>>5): operand row/col = lane&15, K-quarter (32B) = lane>>4.
// C/D: col = lane&15, row = (lane>>4)*4 + reg (guide-verified for 16x16).
__global__ __launch_bounds__(1024, 8)
void kde_gemm(const unsigned char* __restrict__ Xn8, float* __restrict__ density,
              unsigned int* __restrict__ ticket, float* __restrict__ out) {
  extern __shared__ char smem[];
  char* buf0 = smem;           // 32 KB
  char* buf1 = smem + 32768;   // 32 KB

  const int tid = threadIdx.x;
  const int wave = tid >> 6;   // 0..15
  const int lane = tid & 63;
  const int l16 = lane & 15;
  const int lg = lane >> 4;    // K-quarter 0..3
  const int wr = wave >> 1;    // row group 0..7 (16 rows each)
  const int wc = wave & 1;     // col half 0..1 (64 cols each)
  const int m32 = lane & 31;   // staging only
  const int h = lane >> 5;     // staging only
  const int bi = blockIdx.x;
  const int s = blockIdx.y;
  const int t0 = s * 16;
  const int nt = (s == 0 && bi < NT / 2) ? 17 : 16;
  const char* Xb = (const char*)Xn8;

  // Chunk c = rt*8 + kb*2 + hh: lane holds M[rt*32+m32][kb*64+h*32+hh*16 ..+15]
  // 16 waves -> 2 chunks each.
#define STAGE(base_row, dst)                                                      \
  for (int c = wave; c < 32; c += 16) {                                           \
    const int rt = c >> 3, kb = (c >> 1) & 3, hh = c & 1;                         \
    const size_t gofs =                                                           \
        (size_t)((base_row) + rt * 32 + m32) * KDIM + kb * 64 + h * 32 + hh * 16; \
    __builtin_amdgcn_global_load_lds((global_cvoid_t*)(Xb + gofs),                \
                                     (lds_void_t*)((dst) + c * 1024), 16, 0, 0);  \
  }

  STAGE(bi * NTILE, buf0);                      // A tile -> buf0
  STAGE(((bi + t0) & (NT - 1)) * NTILE, buf1);  // B(0)   -> buf1
  __syncthreads();  // both landed (vmcnt drained at barrier)

  // Per-lane invariant LDS offsets.
  // A row part: R = wr*16 + l16 -> rt = wr>>1, m32_a = (wr&1)*16 + l16.
  const int a_row_off = ((wr >> 1) * 8192) + (((wr & 1) * 16 + l16) * 16);
  // K part (kq, p): ((kq*2 + (lg>>1))*2 + p)*1024 + (lg&1)*512
  //              = k_base + kq*4096 + p*1024.
  const int k_base = ((lg >> 1) * 2048) + ((lg & 1) * 512);
  // B row part per coltile ct: wc*16384 + (ct>>1)*8192 + (ct&1)*256 + l16*16.
  const int b_base = wc * 16384 + l16 * 16 + k_base;

  // A fragments -> registers: this wave's 16 rows, full K (16 VGPRs).
  frag32 areg[2];
#pragma unroll
  for (int kq = 0; kq < 2; kq++)
#pragma unroll
    for (int p = 0; p < 2; p++)
      areg[kq].v4[p] =
          *(const i32x4_t*)(buf0 + a_row_off + k_base + kq * 4096 + p * 1024);
  __syncthreads();  // all waves done reading A from buf0

  f32x2_t rs01 = (f32x2_t)0.0f;  // rowsum partials, regs 0,1
  f32x2_t rs23 = (f32x2_t)0.0f;  // regs 2,3

  for (int k = 0; k < nt; ++k) {
    const int t = (k == 16) ? 64 : (t0 + k);
    const int J = (bi + t) & (NT - 1);
    char* rbuf = (k & 1) ? buf0 : buf1;  // B(k): landed at last barrier
    char* sbuf = (k & 1) ? buf1 : buf0;  // free since last barrier

    if (k + 1 < nt) {
      const int tn = (k + 1 == 16) ? 64 : (t0 + k + 1);
      STAGE(((bi + tn) & (NT - 1)) * NTILE, sbuf);
    }

    // 4 coltiles x 2 chained MFMAs; 4 independent dep-chains of 2.
    f32x4_t acc[4];
#pragma unroll
    for (int ct = 0; ct < 4; ct++) acc[ct] = (f32x4_t)0.0f;
#pragma unroll
    for (int ct = 0; ct < 4; ct++) {
      const char* pb = rbuf + b_base + (ct >> 1) * 8192 + (ct & 1) * 256;
#pragma unroll
      for (int kq = 0; kq < 2; kq++) {
        frag32 bf;
        bf.v4[0] = *(const i32x4_t*)(pb + kq * 4096);
        bf.v4[1] = *(const i32x4_t*)(pb + kq * 4096 + 1024);
        acc[ct] = __builtin_amdgcn_mfma_scale_f32_16x16x128_f8f6f4(
            areg[kq].v8, bf.v8, acc[ct], 0, 0, 0, 127, 0, 127);
      }
    }

    // Epilogue: e = exp2(sim_scaled) = exp(5*sim). Rowsums in regs across k;
    // colsum: per-ct 16-row partial reduced over lg (xor 16,32), then ONE
    // coalesced 64-lane atomic (lane ct-select: col = wc*64 + lane).
    float cst[4];
#pragma unroll
    for (int ct = 0; ct < 4; ct++) {
      f32x2_t e01, e23;
      e01.x = EXP2(acc[ct][0]);
      e01.y = EXP2(acc[ct][1]);
      e23.x = EXP2(acc[ct][2]);
      e23.y = EXP2(acc[ct][3]);
      rs01 += e01;  // v_pk_add_f32
      rs23 += e23;
      float cs = (e01.x + e01.y) + (e23.x + e23.y);
      cs += __shfl_xor(cs, 16);  // combine lg bit0
      cs += __shfl_xor(cs, 32);  // combine lg bit1 -> full 16-row colsum
      cst[ct] = cs;
    }
    if (t != 0) {  // diagonal tile (t=0): rowsum only
      const float v = (lg & 2) ? ((lg & 1) ? cst[3] : cst[2])
                               : ((lg & 1) ? cst[1] : cst[0]);
      atomicAdd(&density[J * NTILE + wc * 64 + lane], v);
    }

    __syncthreads();  // B(k+1) landed; all waves done reading rbuf
  }

  // Row epilogue: reduce over 16 cols (l16) per ct-accumulated partials;
  // one atomic instr/wave: lanes l16<4 write rows wr*16 + lg*4 + l16.
  {
    float rsv[4] = {rs01.x, rs01.y, rs23.x, rs23.y};
#pragma unroll
    for (int r = 0; r < 4; r++) {
      float v = rsv[r];
      v += __shfl_xor(v, 1);
      v += __shfl_xor(v, 2);
      v += __shfl_xor(v, 4);
      v += __shfl_xor(v, 8);
      rsv[r] = v;
    }
    const float v = (l16 & 2) ? ((l16 & 1) ? rsv[3] : rsv[2])
                              : ((l16 & 1) ? rsv[1] : rsv[0]);
    if (l16 < 4)  // 2 adds per row (wc=0,1)
      atomicAdd(&density[bi * NTILE + wr * 16 + lg * 4 + l16], v);
  }
#undef STAGE

  // Ticket: last finished block computes the entropy (saves 2 launches).
  __syncthreads();  // all waves' atomics issued & drained (vmcnt(0) at barrier)
  if (tid == 0) {
    __threadfence();
    ((volatile unsigned int*)smem)[0] = atomicAdd(ticket, 1u);
  }
  __syncthreads();
  if (((volatile unsigned int*)smem)[0] == TOTAL_BLOCKS - 1) {
    __threadfence();
    float ssum = 0.0f;
    for (int i = tid; i < NROWS; i += 1024) {
      const float d = __hip_atomic_load(&density[i], __ATOMIC_RELAXED,
                                        __HIP_MEMORY_SCOPE_AGENT);
      ssum += logf(d + 1e-9f);
    }
    ssum += __shfl_xor(ssum, 1);
    ssum += __shfl_xor(ssum, 2);
    ssum += __shfl_xor(ssum, 4);
    ssum += __shfl_xor(ssum, 8);
    ssum += __shfl_xor(ssum, 16);
    ssum += __shfl_xor(ssum, 32);
    float* red = ((float*)smem) + 16;
    if (lane == 0) red[wave] = ssum;
    __syncthreads();
    if (tid == 0) {
      float tot = 0.0f;
      for (int w = 0; w < 16; w++) tot += red[w];
      out[0] = -tot / (float)NROWS;
    }
  }
}

extern "C" void kernel_launch(void* const* d_in, const int* in_sizes, int n_in,
                              void* d_out, int out_size, void* d_ws, size_t ws_size,
                              hipStream_t stream) {
  const float* X = (const float*)d_in[0];
  float* out = (float*)d_out;
  char* ws = (char*)d_ws;
  unsigned int* Xn8 = (unsigned int*)ws;
  float* density = (float*)(ws + (size_t)NROWS * KDIM);
  unsigned int* ticket = (unsigned int*)(density + NROWS);

  hipFuncSetAttribute((const void*)kde_gemm,
                      hipFuncAttributeMaxDynamicSharedMemorySize, 65536);

  kde_normalize<<<NROWS / 4, 256, 0, stream>>>(X, Xn8, density, ticket);
  kde_gemm<<<dim3(NT, NSTRIP), 1024, 65536, stream>>>((const unsigned char*)ws,
                                                      density, ticket, out);
}